// Round 1
// baseline (764.513 us; speedup 1.0000x reference)
//
#include <hip/hip_runtime.h>
#include <stdint.h>
#include <stddef.h>

#define AS1 __attribute__((address_space(1)))
#define AS3 __attribute__((address_space(3)))

typedef short short8 __attribute__((ext_vector_type(8)));   // 8 bf16 (4 VGPRs)
typedef float v4f    __attribute__((ext_vector_type(4)));   // MFMA C/D frag
typedef unsigned short us4 __attribute__((ext_vector_type(4)));

constexpr int S_  = 2048;
constexpr int D_  = 4096;
constexpr int H_  = 32;
constexpr int KV_ = 8;
constexpr int HD_ = 128;
constexpr int NQKV_ = H_*HD_ + 2*KV_*HD_;   // 6144
constexpr float SCALE_ = 0.08838834764831845f;        // 1/sqrt(128)
constexpr float NLOG2T_64 = -0.24390063241307518f;    // -log2(50000)/64

__device__ __forceinline__ unsigned short f2bf(float f){
  union { float f; unsigned u; } v; v.f = f;
  unsigned r = v.u + 0x7FFFu + ((v.u >> 16) & 1u);     // RNE
  return (unsigned short)(r >> 16);
}
__device__ __forceinline__ float bf2f(unsigned short h){
  union { unsigned u; float f; } v; v.u = ((unsigned)h) << 16; return v.f;
}

// async global->LDS, 16B per lane; LDS dst = wave-uniform base + lane*16
__device__ __forceinline__ void gl_lds16(const unsigned short* g, unsigned short* l){
  __builtin_amdgcn_global_load_lds((AS1 unsigned int*)(uintptr_t)g,
                                   (AS3 unsigned int*)l, 16, 0, 0);
}

// ---------------- RMSNorm: hidden fp32 [S][D] -> h bf16 [S][D] ----------------
__global__ __launch_bounds__(256) void rmsnorm_k(const float* __restrict__ hidden,
                                                 const float* __restrict__ w,
                                                 unsigned short* __restrict__ out){
  const int s = blockIdx.x, tid = threadIdx.x;
  const float4* row = (const float4*)(hidden + (size_t)s * D_);
  float4 v[4];
  float ss = 0.f;
  #pragma unroll
  for (int i = 0; i < 4; i++){
    float4 t = row[tid + 256*i]; v[i] = t;
    ss += t.x*t.x + t.y*t.y + t.z*t.z + t.w*t.w;
  }
  #pragma unroll
  for (int off = 32; off >= 1; off >>= 1) ss += __shfl_xor(ss, off, 64);
  __shared__ float wsum[4];
  if ((tid & 63) == 0) wsum[tid >> 6] = ss;
  __syncthreads();
  const float total = wsum[0] + wsum[1] + wsum[2] + wsum[3];
  const float r = rsqrtf(total * (1.0f / D_) + 1e-6f);
  const float4* w4 = (const float4*)w;
  us4* o = (us4*)(out + (size_t)s * D_);
  #pragma unroll
  for (int i = 0; i < 4; i++){
    float4 t = v[i], ww = w4[tid + 256*i];
    us4 p;
    p[0] = f2bf(t.x * r * ww.x); p[1] = f2bf(t.y * r * ww.y);
    p[2] = f2bf(t.z * r * ww.z); p[3] = f2bf(t.w * r * ww.w);
    o[tid + 256*i] = p;
  }
}

// ---------------- fp32 -> bf16 cast ----------------
__global__ __launch_bounds__(256) void cast_k(const float* __restrict__ src,
                                              unsigned short* __restrict__ dst, int n4){
  const int i = blockIdx.x * 256 + threadIdx.x;
  if (i >= n4) return;
  float4 t = ((const float4*)src)[i];
  us4 p;
  p[0] = f2bf(t.x); p[1] = f2bf(t.y); p[2] = f2bf(t.z); p[3] = f2bf(t.w);
  ((us4*)dst)[i] = p;
}

// ---------------- bt-GEMM: C[M,N] = A[M,K] * B[N,K]^T, bf16 in, bf16/f32 out ----
// 128x128 tile, BK=32, 4 waves (2x2 of 64x64), m97 structure.
__global__ __launch_bounds__(256) void gemm_bt(const unsigned short* __restrict__ A,
                                               const unsigned short* __restrict__ B,
                                               void* __restrict__ Cp,
                                               int K, int ldc, int f32out){
  __shared__ __align__(16) unsigned short sA[128*32];
  __shared__ __align__(16) unsigned short sB[128*32];
  const int tid = threadIdx.x;
  const int wave = tid >> 6, lane = tid & 63, l15 = lane & 15, quad = lane >> 4;
  const int m0 = blockIdx.y * 128, n0 = blockIdx.x * 128;
  const int wm = wave & 1, wn = wave >> 1;

  v4f acc[4][4];
  #pragma unroll
  for (int i = 0; i < 4; i++)
    #pragma unroll
    for (int j = 0; j < 4; j++) acc[i][j] = (v4f){0.f,0.f,0.f,0.f};

  const int arow = tid >> 2, acol = (tid & 3) * 8;   // 4 threads per 32-elem row
  const unsigned short* gA = A + (size_t)(m0 + arow) * K + acol;
  const unsigned short* gB = B + (size_t)(n0 + arow) * K + acol;
  unsigned short* lA = sA + wave * 512;   // wave-uniform base (bytes: wave*1024)
  unsigned short* lB = sB + wave * 512;

  for (int kt = 0; kt < K; kt += 32){
    gl_lds16(gA,                 lA);
    gl_lds16(gA + (size_t)64*K,  lA + 2048);
    gl_lds16(gB,                 lB);
    gl_lds16(gB + (size_t)64*K,  lB + 2048);
    gA += 32; gB += 32;
    __syncthreads();            // drains vmcnt: LDS tiles ready

    short8 af[4], bfr[4];
    #pragma unroll
    for (int mt = 0; mt < 4; mt++)
      af[mt] = *(const short8*)(sA + (wm*64 + mt*16 + l15)*32 + quad*8);
    #pragma unroll
    for (int nt = 0; nt < 4; nt++)
      bfr[nt] = *(const short8*)(sB + (wn*64 + nt*16 + l15)*32 + quad*8);
    #pragma unroll
    for (int mt = 0; mt < 4; mt++)
      #pragma unroll
      for (int nt = 0; nt < 4; nt++)
        acc[mt][nt] = __builtin_amdgcn_mfma_f32_16x16x32_bf16(af[mt], bfr[nt], acc[mt][nt], 0, 0, 0);
    __syncthreads();            // protect LDS before next stage
  }

  if (f32out){
    float* Cf = (float*)Cp;
    #pragma unroll
    for (int mt = 0; mt < 4; mt++)
      #pragma unroll
      for (int r = 0; r < 4; r++){
        const size_t row = (size_t)(m0 + wm*64 + mt*16 + quad*4 + r);
        float* crow = Cf + row * ldc + n0 + wn*64 + l15;
        #pragma unroll
        for (int nt = 0; nt < 4; nt++) crow[nt*16] = acc[mt][nt][r];
      }
  } else {
    unsigned short* Cb = (unsigned short*)Cp;
    #pragma unroll
    for (int mt = 0; mt < 4; mt++)
      #pragma unroll
      for (int r = 0; r < 4; r++){
        const size_t row = (size_t)(m0 + wm*64 + mt*16 + quad*4 + r);
        unsigned short* crow = Cb + row * ldc + n0 + wn*64 + l15;
        #pragma unroll
        for (int nt = 0; nt < 4; nt++) crow[nt*16] = f2bf(acc[mt][nt][r]);
      }
  }
}

// ---------------- RoPE on Q: qkv[s][h*128+2j..] -> qa[h][s][128] ----------------
__global__ __launch_bounds__(256) void rope_q_k(const unsigned short* __restrict__ qkv,
                                                unsigned short* __restrict__ qa){
  const int idx = blockIdx.x * 256 + threadIdx.x;     // S*H*64 = 4194304
  const int j = idx & 63, h = (idx >> 6) & (H_-1), s = idx >> 11;
  const unsigned pair = *(const unsigned*)(qkv + (size_t)s*NQKV_ + h*HD_ + 2*j);
  const float x0 = bf2f((unsigned short)(pair & 0xffffu));
  const float x1 = bf2f((unsigned short)(pair >> 16));
  const float ang = (float)s * exp2f((float)j * NLOG2T_64);
  const float c = __cosf(ang), sn = __sinf(ang);
  const unsigned o = (unsigned)f2bf(x0*c - x1*sn) | ((unsigned)f2bf(x0*sn + x1*c) << 16);
  *(unsigned*)(qa + ((size_t)h*S_ + s)*HD_ + 2*j) = o;
}

// ---------------- RoPE on K: qkv[s][4096+kv*128+..] -> ka[kv][s][128] ------------
__global__ __launch_bounds__(256) void rope_kk(const unsigned short* __restrict__ qkv,
                                               unsigned short* __restrict__ ka){
  const int idx = blockIdx.x * 256 + threadIdx.x;     // S*KV*64 = 1048576
  const int j = idx & 63, kv = (idx >> 6) & (KV_-1), s = idx >> 9;
  const unsigned pair = *(const unsigned*)(qkv + (size_t)s*NQKV_ + H_*HD_ + kv*HD_ + 2*j);
  const float x0 = bf2f((unsigned short)(pair & 0xffffu));
  const float x1 = bf2f((unsigned short)(pair >> 16));
  const float ang = (float)s * exp2f((float)j * NLOG2T_64);
  const float c = __cosf(ang), sn = __sinf(ang);
  const unsigned o = (unsigned)f2bf(x0*c - x1*sn) | ((unsigned)f2bf(x0*sn + x1*c) << 16);
  *(unsigned*)(ka + ((size_t)kv*S_ + s)*HD_ + 2*j) = o;
}

// ---------------- V transpose: qkv[s][5120+kv*128+d] -> vt[kv][d][s] -------------
__global__ __launch_bounds__(256) void vtrans_k(const unsigned short* __restrict__ qkv,
                                                unsigned short* __restrict__ vt){
  const int idx = blockIdx.x * 256 + threadIdx.x;     // KV*HD*S = 2097152
  const int s = idx & (S_-1), d = (idx >> 11) & (HD_-1), kv = idx >> 18;
  vt[idx] = qkv[(size_t)s*NQKV_ + (H_+KV_)*HD_ + kv*HD_ + d];
}

// ---------------- flash attention (causal, GQA) ----------------
// grid (H, S/64); 4 waves/block, each wave owns 16 q-rows. LDS only for the
// per-wave P C->A layout round-trip (no cross-wave sharing -> no barriers).
__global__ __launch_bounds__(256) void attn_k(const unsigned short* __restrict__ qa,
                                              const unsigned short* __restrict__ ka,
                                              const unsigned short* __restrict__ vt,
                                              unsigned short* __restrict__ out){
  const int h = blockIdx.x, qb = blockIdx.y;
  const int tid = threadIdx.x, wave = tid >> 6, lane = tid & 63;
  const int l15 = lane & 15, quad = lane >> 4;
  const int hk = h >> 2;                      // N_REP = 4
  const int qr0 = qb * 64 + wave * 16;
  __shared__ __align__(16) unsigned short Plds[4][16*32];
  unsigned short* pl = &Plds[wave][0];

  short8 qf[4];
  {
    const unsigned short* qbase = qa + ((size_t)h*S_ + qr0 + l15)*HD_ + quad*8;
    #pragma unroll
    for (int kk = 0; kk < 4; kk++) qf[kk] = *(const short8*)(qbase + kk*32);
  }
  v4f O[8];
  #pragma unroll
  for (int nt = 0; nt < 8; nt++) O[nt] = (v4f){0.f,0.f,0.f,0.f};
  float mrow[4], lrow[4];
  #pragma unroll
  for (int r = 0; r < 4; r++){ mrow[r] = -1e30f; lrow[r] = 0.f; }

  const int nblk = (qr0 + 47) >> 5;           // keys needed: qr0+16, blocks of 32
  for (int b = 0; b < nblk; b++){
    const int t0 = b * 32;
    v4f s0 = (v4f){0.f,0.f,0.f,0.f}, s1 = (v4f){0.f,0.f,0.f,0.f};
    const unsigned short* kb = ka + ((size_t)hk*S_ + t0 + l15)*HD_ + quad*8;
    #pragma unroll
    for (int kk = 0; kk < 4; kk++){
      short8 kf0 = *(const short8*)(kb + kk*32);
      short8 kf1 = *(const short8*)(kb + 16*HD_ + kk*32);
      s0 = __builtin_amdgcn_mfma_f32_16x16x32_bf16(qf[kk], kf0, s0, 0, 0, 0);
      s1 = __builtin_amdgcn_mfma_f32_16x16x32_bf16(qf[kk], kf1, s1, 0, 0, 0);
    }
    float p0[4], p1[4], alpha[4];
    #pragma unroll
    for (int r = 0; r < 4; r++){
      const int qrow = qr0 + quad*4 + r;
      float a0 = s0[r] * SCALE_; if (t0 + l15 > qrow)      a0 = -1e30f;
      float a1 = s1[r] * SCALE_; if (t0 + 16 + l15 > qrow) a1 = -1e30f;
      float mx = fmaxf(a0, a1);
      #pragma unroll
      for (int off = 1; off < 16; off <<= 1) mx = fmaxf(mx, __shfl_xor(mx, off, 16));
      const float mnew = fmaxf(mrow[r], mx);
      const float al = __expf(mrow[r] - mnew);
      const float e0 = __expf(a0 - mnew);
      const float e1 = __expf(a1 - mnew);
      float rs = e0 + e1;
      #pragma unroll
      for (int off = 1; off < 16; off <<= 1) rs += __shfl_xor(rs, off, 16);
      lrow[r] = lrow[r]*al + rs;
      mrow[r] = mnew;
      alpha[r] = al; p0[r] = e0; p1[r] = e1;
    }
    #pragma unroll
    for (int nt = 0; nt < 8; nt++)
      #pragma unroll
      for (int r = 0; r < 4; r++) O[nt][r] *= alpha[r];

    // P: C-layout -> LDS -> A-layout (per-wave private region)
    #pragma unroll
    for (int r = 0; r < 4; r++){
      pl[(quad*4 + r)*32 + l15]      = f2bf(p0[r]);
      pl[(quad*4 + r)*32 + 16 + l15] = f2bf(p1[r]);
    }
    __builtin_amdgcn_s_waitcnt(0xC07F);       // lgkmcnt(0)
    const short8 pf = *(const short8*)(pl + l15*32 + quad*8);
    const unsigned short* vb = vt + ((size_t)hk*HD_ + l15)*S_ + t0 + quad*8;
    #pragma unroll
    for (int nt = 0; nt < 8; nt++){
      short8 vf = *(const short8*)(vb + (size_t)nt*16*S_);
      O[nt] = __builtin_amdgcn_mfma_f32_16x16x32_bf16(pf, vf, O[nt], 0, 0, 0);
    }
  }

  float inv[4];
  #pragma unroll
  for (int r = 0; r < 4; r++) inv[r] = 1.0f / lrow[r];
  #pragma unroll
  for (int nt = 0; nt < 8; nt++)
    #pragma unroll
    for (int r = 0; r < 4; r++)
      out[(size_t)(qr0 + quad*4 + r)*D_ + h*HD_ + nt*16 + l15] = f2bf(O[nt][r] * inv[r]);
}

// ---------------- launch ----------------
// Workspace map (MiB): [0,16) h_bf16 | [16,64) wqkv_bf16 (later: [16,48) wo_bf16,
// [48,64) attn_bf16) | [64,88) qkv_bf16 | [88,104) qa | [104,108) ka | [108,112) vt.
// Requires ws_size >= 112 MiB.
extern "C" void kernel_launch(void* const* d_in, const int* in_sizes, int n_in,
                              void* d_out, int out_size, void* d_ws, size_t ws_size,
                              hipStream_t stream){
  (void)in_sizes; (void)n_in; (void)out_size; (void)ws_size;
  const float* hidden = (const float*)d_in[0];
  const float* norm_w = (const float*)d_in[1];
  const float* wq = (const float*)d_in[2];
  const float* wk = (const float*)d_in[3];
  const float* wv = (const float*)d_in[4];
  const float* wo = (const float*)d_in[5];

  char* ws = (char*)d_ws;
  unsigned short* h_bf  = (unsigned short*)(ws);
  unsigned short* wqkv  = (unsigned short*)(ws + (size_t)(16u) * 1048576u);
  unsigned short* qkv   = (unsigned short*)(ws + (size_t)(64u) * 1048576u);
  unsigned short* qa    = (unsigned short*)(ws + (size_t)(88u) * 1048576u);
  unsigned short* ka    = (unsigned short*)(ws + (size_t)(104u) * 1048576u);
  unsigned short* vt    = (unsigned short*)(ws + (size_t)(108u) * 1048576u);
  unsigned short* wo_bf = (unsigned short*)(ws + (size_t)(16u) * 1048576u);  // reuse
  unsigned short* attnb = (unsigned short*)(ws + (size_t)(48u) * 1048576u);  // reuse

  rmsnorm_k<<<S_, 256, 0, stream>>>(hidden, norm_w, h_bf);

  cast_k<<<(D_*D_/4)/256, 256, 0, stream>>>(wq, wqkv, D_*D_/4);
  cast_k<<<(KV_*HD_*D_/4)/256, 256, 0, stream>>>(wk, wqkv + (size_t)H_*HD_*D_, KV_*HD_*D_/4);
  cast_k<<<(KV_*HD_*D_/4)/256, 256, 0, stream>>>(wv, wqkv + (size_t)(H_+KV_)*HD_*D_, KV_*HD_*D_/4);

  gemm_bt<<<dim3(NQKV_/128, S_/128), 256, 0, stream>>>(h_bf, wqkv, qkv, D_, NQKV_, 0);

  rope_q_k<<<(S_*H_*64)/256, 256, 0, stream>>>(qkv, qa);
  rope_kk <<<(S_*KV_*64)/256, 256, 0, stream>>>(qkv, ka);
  vtrans_k<<<(KV_*HD_*S_)/256, 256, 0, stream>>>(qkv, vt);

  cast_k<<<(D_*D_/4)/256, 256, 0, stream>>>(wo, wo_bf, D_*D_/4);   // after QKV GEMM (buffer reuse)

  attn_k<<<dim3(H_, S_/64), 256, 0, stream>>>(qa, ka, vt, attnb);

  gemm_bt<<<dim3(D_/128, S_/128), 256, 0, stream>>>(attnb, wo_bf, d_out, D_, D_, 1);
}

// Round 2
// 626.175 us; speedup vs baseline: 1.2209x; 1.2209x over previous
//
#include <hip/hip_runtime.h>
#include <stdint.h>
#include <stddef.h>

#define AS1 __attribute__((address_space(1)))
#define AS3 __attribute__((address_space(3)))

typedef short short8 __attribute__((ext_vector_type(8)));   // 8 bf16 (4 VGPRs)
typedef float v4f    __attribute__((ext_vector_type(4)));   // MFMA C/D frag
typedef unsigned short us4 __attribute__((ext_vector_type(4)));

constexpr int S_  = 2048;
constexpr int D_  = 4096;
constexpr int H_  = 32;
constexpr int KV_ = 8;
constexpr int HD_ = 128;
constexpr int NQKV_ = H_*HD_ + 2*KV_*HD_;   // 6144
constexpr float SCALE_L2E = 0.12751744154070513f;  // (1/sqrt(128)) * log2(e)
constexpr float NLOG2T_64 = -0.24390063241307518f; // -log2(50000)/64

__device__ __forceinline__ unsigned short f2bf(float f){
  union { float f; unsigned u; } v; v.f = f;
  unsigned r = v.u + 0x7FFFu + ((v.u >> 16) & 1u);     // RNE
  return (unsigned short)(r >> 16);
}
__device__ __forceinline__ float bf2f(unsigned short h){
  union { unsigned u; float f; } v; v.u = ((unsigned)h) << 16; return v.f;
}

// async global->LDS, 16B per lane; LDS dst = wave-uniform base + lane*16
__device__ __forceinline__ void gl_lds16(const unsigned short* g, unsigned short* l){
  __builtin_amdgcn_global_load_lds((AS1 unsigned int*)(uintptr_t)g,
                                   (AS3 unsigned int*)l, 16, 0, 0);
}

// ---------------- RMSNorm: hidden fp32 [S][D] -> h bf16 [S][D] ----------------
__global__ __launch_bounds__(256) void rmsnorm_k(const float* __restrict__ hidden,
                                                 const float* __restrict__ w,
                                                 unsigned short* __restrict__ out){
  const int s = blockIdx.x, tid = threadIdx.x;
  const float4* row = (const float4*)(hidden + (size_t)s * D_);
  float4 v[4];
  float ss = 0.f;
  #pragma unroll
  for (int i = 0; i < 4; i++){
    float4 t = row[tid + 256*i]; v[i] = t;
    ss += t.x*t.x + t.y*t.y + t.z*t.z + t.w*t.w;
  }
  #pragma unroll
  for (int off = 32; off >= 1; off >>= 1) ss += __shfl_xor(ss, off, 64);
  __shared__ float wsum[4];
  if ((tid & 63) == 0) wsum[tid >> 6] = ss;
  __syncthreads();
  const float total = wsum[0] + wsum[1] + wsum[2] + wsum[3];
  const float r = rsqrtf(total * (1.0f / D_) + 1e-6f);
  const float4* w4 = (const float4*)w;
  us4* o = (us4*)(out + (size_t)s * D_);
  #pragma unroll
  for (int i = 0; i < 4; i++){
    float4 t = v[i], ww = w4[tid + 256*i];
    us4 p;
    p[0] = f2bf(t.x * r * ww.x); p[1] = f2bf(t.y * r * ww.y);
    p[2] = f2bf(t.z * r * ww.z); p[3] = f2bf(t.w * r * ww.w);
    o[tid + 256*i] = p;
  }
}

// ---------------- fp32 -> bf16 cast ----------------
__global__ __launch_bounds__(256) void cast_k(const float* __restrict__ src,
                                              unsigned short* __restrict__ dst, int n4){
  const int i = blockIdx.x * 256 + threadIdx.x;
  if (i >= n4) return;
  float4 t = ((const float4*)src)[i];
  us4 p;
  p[0] = f2bf(t.x); p[1] = f2bf(t.y); p[2] = f2bf(t.z); p[3] = f2bf(t.w);
  ((us4*)dst)[i] = p;
}

// ---------------- bt-GEMM: C[M,N] = A[M,K] * B[N,K]^T, bf16 in, bf16/f32 out ----
__global__ __launch_bounds__(256) void gemm_bt(const unsigned short* __restrict__ A,
                                               const unsigned short* __restrict__ B,
                                               void* __restrict__ Cp,
                                               int K, int ldc, int f32out){
  __shared__ __align__(16) unsigned short sA[128*32];
  __shared__ __align__(16) unsigned short sB[128*32];
  const int tid = threadIdx.x;
  const int wave = tid >> 6, lane = tid & 63, l15 = lane & 15, quad = lane >> 4;
  const int m0 = blockIdx.y * 128, n0 = blockIdx.x * 128;
  const int wm = wave & 1, wn = wave >> 1;

  v4f acc[4][4];
  #pragma unroll
  for (int i = 0; i < 4; i++)
    #pragma unroll
    for (int j = 0; j < 4; j++) acc[i][j] = (v4f){0.f,0.f,0.f,0.f};

  const int arow = tid >> 2, acol = (tid & 3) * 8;
  const unsigned short* gA = A + (size_t)(m0 + arow) * K + acol;
  const unsigned short* gB = B + (size_t)(n0 + arow) * K + acol;
  unsigned short* lA = sA + wave * 512;
  unsigned short* lB = sB + wave * 512;

  for (int kt = 0; kt < K; kt += 32){
    gl_lds16(gA,                 lA);
    gl_lds16(gA + (size_t)64*K,  lA + 2048);
    gl_lds16(gB,                 lB);
    gl_lds16(gB + (size_t)64*K,  lB + 2048);
    gA += 32; gB += 32;
    __syncthreads();

    short8 af[4], bfr[4];
    #pragma unroll
    for (int mt = 0; mt < 4; mt++)
      af[mt] = *(const short8*)(sA + (wm*64 + mt*16 + l15)*32 + quad*8);
    #pragma unroll
    for (int nt = 0; nt < 4; nt++)
      bfr[nt] = *(const short8*)(sB + (wn*64 + nt*16 + l15)*32 + quad*8);
    #pragma unroll
    for (int mt = 0; mt < 4; mt++)
      #pragma unroll
      for (int nt = 0; nt < 4; nt++)
        acc[mt][nt] = __builtin_amdgcn_mfma_f32_16x16x32_bf16(af[mt], bfr[nt], acc[mt][nt], 0, 0, 0);
    __syncthreads();
  }

  if (f32out){
    float* Cf = (float*)Cp;
    #pragma unroll
    for (int mt = 0; mt < 4; mt++)
      #pragma unroll
      for (int r = 0; r < 4; r++){
        const size_t row = (size_t)(m0 + wm*64 + mt*16 + quad*4 + r);
        float* crow = Cf + row * ldc + n0 + wn*64 + l15;
        #pragma unroll
        for (int nt = 0; nt < 4; nt++) crow[nt*16] = acc[mt][nt][r];
      }
  } else {
    unsigned short* Cb = (unsigned short*)Cp;
    #pragma unroll
    for (int mt = 0; mt < 4; mt++)
      #pragma unroll
      for (int r = 0; r < 4; r++){
        const size_t row = (size_t)(m0 + wm*64 + mt*16 + quad*4 + r);
        unsigned short* crow = Cb + row * ldc + n0 + wn*64 + l15;
        #pragma unroll
        for (int nt = 0; nt < 4; nt++) crow[nt*16] = f2bf(acc[mt][nt][r]);
      }
  }
}

// ---------------- RoPE on Q: qkv[s][h*128+2j..] -> qa[h][s][128] ----------------
__global__ __launch_bounds__(256) void rope_q_k(const unsigned short* __restrict__ qkv,
                                                unsigned short* __restrict__ qa){
  const int idx = blockIdx.x * 256 + threadIdx.x;
  const int j = idx & 63, h = (idx >> 6) & (H_-1), s = idx >> 11;
  const unsigned pair = *(const unsigned*)(qkv + (size_t)s*NQKV_ + h*HD_ + 2*j);
  const float x0 = bf2f((unsigned short)(pair & 0xffffu));
  const float x1 = bf2f((unsigned short)(pair >> 16));
  const float ang = (float)s * exp2f((float)j * NLOG2T_64);
  const float c = __cosf(ang), sn = __sinf(ang);
  const unsigned o = (unsigned)f2bf(x0*c - x1*sn) | ((unsigned)f2bf(x0*sn + x1*c) << 16);
  *(unsigned*)(qa + ((size_t)h*S_ + s)*HD_ + 2*j) = o;
}

// ---------------- RoPE on K: qkv[s][4096+kv*128+..] -> ka[kv][s][128] ------------
__global__ __launch_bounds__(256) void rope_kk(const unsigned short* __restrict__ qkv,
                                               unsigned short* __restrict__ ka){
  const int idx = blockIdx.x * 256 + threadIdx.x;
  const int j = idx & 63, kv = (idx >> 6) & (KV_-1), s = idx >> 9;
  const unsigned pair = *(const unsigned*)(qkv + (size_t)s*NQKV_ + H_*HD_ + kv*HD_ + 2*j);
  const float x0 = bf2f((unsigned short)(pair & 0xffffu));
  const float x1 = bf2f((unsigned short)(pair >> 16));
  const float ang = (float)s * exp2f((float)j * NLOG2T_64);
  const float c = __cosf(ang), sn = __sinf(ang);
  const unsigned o = (unsigned)f2bf(x0*c - x1*sn) | ((unsigned)f2bf(x0*sn + x1*c) << 16);
  *(unsigned*)(ka + ((size_t)kv*S_ + s)*HD_ + 2*j) = o;
}

// ---------------- V transpose: qkv[s][5120+kv*128+d] -> vt[kv][d][s] -------------
__global__ __launch_bounds__(256) void vtrans_k(const unsigned short* __restrict__ qkv,
                                                unsigned short* __restrict__ vt){
  const int idx = blockIdx.x * 256 + threadIdx.x;
  const int s = idx & (S_-1), d = (idx >> 11) & (HD_-1), kv = idx >> 18;
  vt[idx] = qkv[(size_t)s*NQKV_ + (H_+KV_)*HD_ + kv*HD_ + d];
}

// ---------------- flash attention (causal, GQA), LDS double-buffered ----------------
// grid (H, S/128). Block: 4 waves, wave w owns q-rows [qb*128+w*32, +32) (2 MFMA
// row-tiles). K-step 64 keys. K/V tiles staged via global_load_lds in FRAGMENT-ORDER
// granules: LDS offset = (tile_group*64 + lane)*16B so every ds_read_b128 is
// stride-1 across lanes (conflict-free); the global gather pattern supplies the
// permutation (global_load_lds LDS side is always base+lane*16).
__device__ __forceinline__ void stage_kv(const unsigned short* __restrict__ ka,
                                         const unsigned short* __restrict__ vt,
                                         unsigned short* sKbuf, unsigned short* sVbuf,
                                         int hk, int t0, int wave, int lane){
  const int l15 = lane & 15, quad = lane >> 4;
  #pragma unroll
  for (int j = 0; j < 4; j++){
    const int c = wave*4 + j;                 // (kt,kk) = (c>>2, c&3)
    const int kt = c >> 2, kk = c & 3;
    gl_lds16(ka + (size_t)(hk*S_ + t0 + kt*16 + l15)*HD_ + kk*32 + quad*8,
             sKbuf + c*512);
  }
  #pragma unroll
  for (int j = 0; j < 4; j++){
    const int c = wave*4 + j;                 // (nt,kk2) = (c>>1, c&1)
    const int nt = c >> 1, kk2 = c & 1;
    gl_lds16(vt + (size_t)(hk*HD_ + nt*16 + l15)*S_ + t0 + kk2*32 + quad*8,
             sVbuf + c*512);
  }
}

__global__ __launch_bounds__(256, 2) void attn_k(const unsigned short* __restrict__ qa,
                                                 const unsigned short* __restrict__ ka,
                                                 const unsigned short* __restrict__ vt,
                                                 unsigned short* __restrict__ out){
  const int h = blockIdx.x, qb = blockIdx.y;
  const int tid = threadIdx.x, wave = tid >> 6, lane = tid & 63;
  const int l15 = lane & 15, quad = lane >> 4;
  const int hk = h >> 2;                      // N_REP = 4
  const int qr0 = qb * 128 + wave * 32;

  __shared__ __align__(16) unsigned short sK[2][8192];   // 16KB x2
  __shared__ __align__(16) unsigned short sV[2][8192];   // 16KB x2
  __shared__ __align__(16) unsigned short sP[4][2048];   // 4KB per wave
  unsigned short* pl = &sP[wave][0];

  // Q fragments: 2 row-tiles x 4 k-chunks
  short8 qf[2][4];
  #pragma unroll
  for (int qt = 0; qt < 2; qt++)
    #pragma unroll
    for (int kk = 0; kk < 4; kk++)
      qf[qt][kk] = *(const short8*)(qa + (size_t)(h*S_ + qr0 + qt*16 + l15)*HD_ + kk*32 + quad*8);

  v4f O[2][8];
  #pragma unroll
  for (int qt = 0; qt < 2; qt++)
    #pragma unroll
    for (int nt = 0; nt < 8; nt++) O[qt][nt] = (v4f){0.f,0.f,0.f,0.f};
  float mrow[2][4], lrow[2][4];
  #pragma unroll
  for (int qt = 0; qt < 2; qt++)
    #pragma unroll
    for (int r = 0; r < 4; r++){ mrow[qt][r] = -1e30f; lrow[qt][r] = 0.f; }

  const int nblk = 2*qb + 2;                  // 64-key blocks; all waves iterate same count

  stage_kv(ka, vt, sK[0], sV[0], hk, 0, wave, lane);
  __syncthreads();

  for (int b = 0; b < nblk; b++){
    const int t0 = b * 64;
    const int cur = b & 1;
    if (b + 1 < nblk)
      stage_kv(ka, vt, sK[cur^1], sV[cur^1], hk, t0 + 64, wave, lane);

    // ---- QK^T: S[32 q-rows x 64 keys] ----
    const unsigned short* Kb = &sK[cur][0];
    v4f sc[2][4];
    #pragma unroll
    for (int qt = 0; qt < 2; qt++)
      #pragma unroll
      for (int kt = 0; kt < 4; kt++) sc[qt][kt] = (v4f){0.f,0.f,0.f,0.f};
    #pragma unroll
    for (int kt = 0; kt < 4; kt++)
      #pragma unroll
      for (int kk = 0; kk < 4; kk++){
        const short8 kf = *(const short8*)(Kb + (kt*4 + kk)*512 + lane*8);
        sc[0][kt] = __builtin_amdgcn_mfma_f32_16x16x32_bf16(qf[0][kk], kf, sc[0][kt], 0, 0, 0);
        sc[1][kt] = __builtin_amdgcn_mfma_f32_16x16x32_bf16(qf[1][kk], kf, sc[1][kt], 0, 0, 0);
      }

    // ---- online softmax (exp2 domain) + P write ----
    #pragma unroll
    for (int qt = 0; qt < 2; qt++){
      const int rowq = qr0 + qt*16 + quad*4;
      const bool needMask = (t0 + 63 > qr0 + qt*16);   // wave-uniform
      float alpha[4];
      #pragma unroll
      for (int r = 0; r < 4; r++){
        float a0 = sc[qt][0][r] * SCALE_L2E;
        float a1 = sc[qt][1][r] * SCALE_L2E;
        float a2 = sc[qt][2][r] * SCALE_L2E;
        float a3 = sc[qt][3][r] * SCALE_L2E;
        if (needMask){
          const int row = rowq + r;
          if (t0      + l15 > row) a0 = -1e30f;
          if (t0 + 16 + l15 > row) a1 = -1e30f;
          if (t0 + 32 + l15 > row) a2 = -1e30f;
          if (t0 + 48 + l15 > row) a3 = -1e30f;
        }
        float mx = fmaxf(fmaxf(a0, a1), fmaxf(a2, a3));
        #pragma unroll
        for (int off = 1; off < 16; off <<= 1) mx = fmaxf(mx, __shfl_xor(mx, off, 16));
        const float mnew = fmaxf(mrow[qt][r], mx);
        const float al = exp2f(mrow[qt][r] - mnew);
        const float e0 = exp2f(a0 - mnew);
        const float e1 = exp2f(a1 - mnew);
        const float e2 = exp2f(a2 - mnew);
        const float e3 = exp2f(a3 - mnew);
        float rs = (e0 + e1) + (e2 + e3);
        #pragma unroll
        for (int off = 1; off < 16; off <<= 1) rs += __shfl_xor(rs, off, 16);
        lrow[qt][r] = lrow[qt][r]*al + rs;
        mrow[qt][r] = mnew;
        alpha[r] = al;
        // P in fragment-order granules: group (qt, kk2=kt>>1)
        pl[(qt*2 + 0)*512 + (0 + (l15>>3))*128 + (quad*4+r)*8 + (l15&7)] = f2bf(e0);
        pl[(qt*2 + 0)*512 + (2 + (l15>>3))*128 + (quad*4+r)*8 + (l15&7)] = f2bf(e1);
        pl[(qt*2 + 1)*512 + (0 + (l15>>3))*128 + (quad*4+r)*8 + (l15&7)] = f2bf(e2);
        pl[(qt*2 + 1)*512 + (2 + (l15>>3))*128 + (quad*4+r)*8 + (l15&7)] = f2bf(e3);
      }
      #pragma unroll
      for (int nt = 0; nt < 8; nt++)
        #pragma unroll
        for (int r = 0; r < 4; r++) O[qt][nt][r] *= alpha[r];
    }

    __builtin_amdgcn_s_waitcnt(0xC07F);       // lgkmcnt(0): P writes visible (per-wave region)
    short8 pf[2][2];
    #pragma unroll
    for (int qt = 0; qt < 2; qt++)
      #pragma unroll
      for (int kk2 = 0; kk2 < 2; kk2++)
        pf[qt][kk2] = *(const short8*)(pl + (qt*2 + kk2)*512 + lane*8);

    // ---- PV: O[32 q-rows x 128 dims] ----
    const unsigned short* Vb = &sV[cur][0];
    #pragma unroll
    for (int nt = 0; nt < 8; nt++)
      #pragma unroll
      for (int kk2 = 0; kk2 < 2; kk2++){
        const short8 vf = *(const short8*)(Vb + (nt*2 + kk2)*512 + lane*8);
        O[0][nt] = __builtin_amdgcn_mfma_f32_16x16x32_bf16(pf[0][kk2], vf, O[0][nt], 0, 0, 0);
        O[1][nt] = __builtin_amdgcn_mfma_f32_16x16x32_bf16(pf[1][kk2], vf, O[1][nt], 0, 0, 0);
      }

    __syncthreads();   // all waves done with cur; prefetch (issued above) drained
  }

  #pragma unroll
  for (int qt = 0; qt < 2; qt++){
    float inv[4];
    #pragma unroll
    for (int r = 0; r < 4; r++) inv[r] = 1.0f / lrow[qt][r];
    #pragma unroll
    for (int nt = 0; nt < 8; nt++)
      #pragma unroll
      for (int r = 0; r < 4; r++)
        out[(size_t)(qr0 + qt*16 + quad*4 + r)*D_ + h*HD_ + nt*16 + l15] = f2bf(O[qt][nt][r] * inv[r]);
  }
}

// ---------------- launch ----------------
// Workspace map (MiB): [0,16) h_bf16 | [16,64) wqkv_bf16 (later: [16,48) wo_bf16,
// [48,64) attn_bf16) | [64,88) qkv_bf16 | [88,104) qa | [104,108) ka | [108,112) vt.
extern "C" void kernel_launch(void* const* d_in, const int* in_sizes, int n_in,
                              void* d_out, int out_size, void* d_ws, size_t ws_size,
                              hipStream_t stream){
  (void)in_sizes; (void)n_in; (void)out_size; (void)ws_size;
  const float* hidden = (const float*)d_in[0];
  const float* norm_w = (const float*)d_in[1];
  const float* wq = (const float*)d_in[2];
  const float* wk = (const float*)d_in[3];
  const float* wv = (const float*)d_in[4];
  const float* wo = (const float*)d_in[5];

  char* ws = (char*)d_ws;
  unsigned short* h_bf  = (unsigned short*)(ws);
  unsigned short* wqkv  = (unsigned short*)(ws + (size_t)(16u) * 1048576u);
  unsigned short* qkv   = (unsigned short*)(ws + (size_t)(64u) * 1048576u);
  unsigned short* qa    = (unsigned short*)(ws + (size_t)(88u) * 1048576u);
  unsigned short* ka    = (unsigned short*)(ws + (size_t)(104u) * 1048576u);
  unsigned short* vt    = (unsigned short*)(ws + (size_t)(108u) * 1048576u);
  unsigned short* wo_bf = (unsigned short*)(ws + (size_t)(16u) * 1048576u);  // reuse
  unsigned short* attnb = (unsigned short*)(ws + (size_t)(48u) * 1048576u);  // reuse

  rmsnorm_k<<<S_, 256, 0, stream>>>(hidden, norm_w, h_bf);

  cast_k<<<(D_*D_/4)/256, 256, 0, stream>>>(wq, wqkv, D_*D_/4);
  cast_k<<<(KV_*HD_*D_/4)/256, 256, 0, stream>>>(wk, wqkv + (size_t)H_*HD_*D_, KV_*HD_*D_/4);
  cast_k<<<(KV_*HD_*D_/4)/256, 256, 0, stream>>>(wv, wqkv + (size_t)(H_+KV_)*HD_*D_, KV_*HD_*D_/4);

  gemm_bt<<<dim3(NQKV_/128, S_/128), 256, 0, stream>>>(h_bf, wqkv, qkv, D_, NQKV_, 0);

  rope_q_k<<<(S_*H_*64)/256, 256, 0, stream>>>(qkv, qa);
  rope_kk <<<(S_*KV_*64)/256, 256, 0, stream>>>(qkv, ka);
  vtrans_k<<<(KV_*HD_*S_)/256, 256, 0, stream>>>(qkv, vt);

  cast_k<<<(D_*D_/4)/256, 256, 0, stream>>>(wo, wo_bf, D_*D_/4);

  attn_k<<<dim3(H_, S_/128), 256, 0, stream>>>(qa, ka, vt, attnb);

  gemm_bt<<<dim3(D_/128, S_/128), 256, 0, stream>>>(attnb, wo_bf, d_out, D_, D_, 1);
}

// Round 3
// 556.840 us; speedup vs baseline: 1.3729x; 1.1245x over previous
//
#include <hip/hip_runtime.h>
#include <stdint.h>
#include <stddef.h>

#define AS1 __attribute__((address_space(1)))
#define AS3 __attribute__((address_space(3)))

typedef short short8 __attribute__((ext_vector_type(8)));   // 8 bf16 (4 VGPRs)
typedef float v4f    __attribute__((ext_vector_type(4)));   // MFMA C/D frag
typedef unsigned short us4 __attribute__((ext_vector_type(4)));

constexpr int S_  = 2048;
constexpr int D_  = 4096;
constexpr int H_  = 32;
constexpr int KV_ = 8;
constexpr int HD_ = 128;
constexpr int NQKV_ = H_*HD_ + 2*KV_*HD_;   // 6144
constexpr float SCALE_L2E = 0.12751744154070513f;  // (1/sqrt(128)) * log2(e)
constexpr float NLOG2T_64 = -0.24390063241307518f; // -log2(50000)/64

__device__ __forceinline__ unsigned short f2bf(float f){
  union { float f; unsigned u; } v; v.f = f;
  unsigned r = v.u + 0x7FFFu + ((v.u >> 16) & 1u);     // RNE
  return (unsigned short)(r >> 16);
}
__device__ __forceinline__ float bf2f(unsigned short h){
  union { unsigned u; float f; } v; v.u = ((unsigned)h) << 16; return v.f;
}

// async global->LDS, 16B per lane; LDS dst = wave-uniform base + lane*16
__device__ __forceinline__ void gl_lds16(const unsigned short* g, unsigned short* l){
  __builtin_amdgcn_global_load_lds((AS1 unsigned int*)(uintptr_t)g,
                                   (AS3 unsigned int*)l, 16, 0, 0);
}

// ---------------- RMSNorm: hidden fp32 [S][D] -> h bf16 [S][D] ----------------
__global__ __launch_bounds__(256) void rmsnorm_k(const float* __restrict__ hidden,
                                                 const float* __restrict__ w,
                                                 unsigned short* __restrict__ out){
  const int s = blockIdx.x, tid = threadIdx.x;
  const float4* row = (const float4*)(hidden + (size_t)s * D_);
  float4 v[4];
  float ss = 0.f;
  #pragma unroll
  for (int i = 0; i < 4; i++){
    float4 t = row[tid + 256*i]; v[i] = t;
    ss += t.x*t.x + t.y*t.y + t.z*t.z + t.w*t.w;
  }
  #pragma unroll
  for (int off = 32; off >= 1; off >>= 1) ss += __shfl_xor(ss, off, 64);
  __shared__ float wsum[4];
  if ((tid & 63) == 0) wsum[tid >> 6] = ss;
  __syncthreads();
  const float total = wsum[0] + wsum[1] + wsum[2] + wsum[3];
  const float r = rsqrtf(total * (1.0f / D_) + 1e-6f);
  const float4* w4 = (const float4*)w;
  us4* o = (us4*)(out + (size_t)s * D_);
  #pragma unroll
  for (int i = 0; i < 4; i++){
    float4 t = v[i], ww = w4[tid + 256*i];
    us4 p;
    p[0] = f2bf(t.x * r * ww.x); p[1] = f2bf(t.y * r * ww.y);
    p[2] = f2bf(t.z * r * ww.z); p[3] = f2bf(t.w * r * ww.w);
    o[tid + 256*i] = p;
  }
}

// ---------------- fp32 -> bf16 cast ----------------
__global__ __launch_bounds__(256) void cast_k(const float* __restrict__ src,
                                              unsigned short* __restrict__ dst, int n4){
  const int i = blockIdx.x * 256 + threadIdx.x;
  if (i >= n4) return;
  float4 t = ((const float4*)src)[i];
  us4 p;
  p[0] = f2bf(t.x); p[1] = f2bf(t.y); p[2] = f2bf(t.z); p[3] = f2bf(t.w);
  ((us4*)dst)[i] = p;
}

// ---------------- bt-GEMM: C[M,N] = A[M,K] * B[N,K]^T, bf16 in, bf16/f32 out ----
__global__ __launch_bounds__(256) void gemm_bt(const unsigned short* __restrict__ A,
                                               const unsigned short* __restrict__ B,
                                               void* __restrict__ Cp,
                                               int K, int ldc, int f32out){
  __shared__ __align__(16) unsigned short sA[128*32];
  __shared__ __align__(16) unsigned short sB[128*32];
  const int tid = threadIdx.x;
  const int wave = tid >> 6, lane = tid & 63, l15 = lane & 15, quad = lane >> 4;
  const int m0 = blockIdx.y * 128, n0 = blockIdx.x * 128;
  const int wm = wave & 1, wn = wave >> 1;

  v4f acc[4][4];
  #pragma unroll
  for (int i = 0; i < 4; i++)
    #pragma unroll
    for (int j = 0; j < 4; j++) acc[i][j] = (v4f){0.f,0.f,0.f,0.f};

  const int arow = tid >> 2, acol = (tid & 3) * 8;
  const unsigned short* gA = A + (size_t)(m0 + arow) * K + acol;
  const unsigned short* gB = B + (size_t)(n0 + arow) * K + acol;
  unsigned short* lA = sA + wave * 512;
  unsigned short* lB = sB + wave * 512;

  for (int kt = 0; kt < K; kt += 32){
    gl_lds16(gA,                 lA);
    gl_lds16(gA + (size_t)64*K,  lA + 2048);
    gl_lds16(gB,                 lB);
    gl_lds16(gB + (size_t)64*K,  lB + 2048);
    gA += 32; gB += 32;
    __syncthreads();

    short8 af[4], bfr[4];
    #pragma unroll
    for (int mt = 0; mt < 4; mt++)
      af[mt] = *(const short8*)(sA + (wm*64 + mt*16 + l15)*32 + quad*8);
    #pragma unroll
    for (int nt = 0; nt < 4; nt++)
      bfr[nt] = *(const short8*)(sB + (wn*64 + nt*16 + l15)*32 + quad*8);
    #pragma unroll
    for (int mt = 0; mt < 4; mt++)
      #pragma unroll
      for (int nt = 0; nt < 4; nt++)
        acc[mt][nt] = __builtin_amdgcn_mfma_f32_16x16x32_bf16(af[mt], bfr[nt], acc[mt][nt], 0, 0, 0);
    __syncthreads();
  }

  if (f32out){
    float* Cf = (float*)Cp;
    #pragma unroll
    for (int mt = 0; mt < 4; mt++)
      #pragma unroll
      for (int r = 0; r < 4; r++){
        const size_t row = (size_t)(m0 + wm*64 + mt*16 + quad*4 + r);
        float* crow = Cf + row * ldc + n0 + wn*64 + l15;
        #pragma unroll
        for (int nt = 0; nt < 4; nt++) crow[nt*16] = acc[mt][nt][r];
      }
  } else {
    unsigned short* Cb = (unsigned short*)Cp;
    #pragma unroll
    for (int mt = 0; mt < 4; mt++)
      #pragma unroll
      for (int r = 0; r < 4; r++){
        const size_t row = (size_t)(m0 + wm*64 + mt*16 + quad*4 + r);
        unsigned short* crow = Cb + row * ldc + n0 + wn*64 + l15;
        #pragma unroll
        for (int nt = 0; nt < 4; nt++) crow[nt*16] = f2bf(acc[mt][nt][r]);
      }
  }
}

// ---- RoPE on Q (PRE-SCALED by 1/sqrt(HD)*log2e): qkv -> qa[h][s][128] ----
__global__ __launch_bounds__(256) void rope_q_k(const unsigned short* __restrict__ qkv,
                                                unsigned short* __restrict__ qa){
  const int idx = blockIdx.x * 256 + threadIdx.x;
  const int j = idx & 63, h = (idx >> 6) & (H_-1), s = idx >> 11;
  const unsigned pair = *(const unsigned*)(qkv + (size_t)s*NQKV_ + h*HD_ + 2*j);
  const float x0 = bf2f((unsigned short)(pair & 0xffffu));
  const float x1 = bf2f((unsigned short)(pair >> 16));
  const float ang = (float)s * exp2f((float)j * NLOG2T_64);
  const float c = __cosf(ang), sn = __sinf(ang);
  const unsigned o = (unsigned)f2bf((x0*c - x1*sn) * SCALE_L2E)
                   | ((unsigned)f2bf((x0*sn + x1*c) * SCALE_L2E) << 16);
  *(unsigned*)(qa + ((size_t)h*S_ + s)*HD_ + 2*j) = o;
}

// ---------------- RoPE on K: qkv[s][4096+kv*128+..] -> ka[kv][s][128] ------------
__global__ __launch_bounds__(256) void rope_kk(const unsigned short* __restrict__ qkv,
                                               unsigned short* __restrict__ ka){
  const int idx = blockIdx.x * 256 + threadIdx.x;
  const int j = idx & 63, kv = (idx >> 6) & (KV_-1), s = idx >> 9;
  const unsigned pair = *(const unsigned*)(qkv + (size_t)s*NQKV_ + H_*HD_ + kv*HD_ + 2*j);
  const float x0 = bf2f((unsigned short)(pair & 0xffffu));
  const float x1 = bf2f((unsigned short)(pair >> 16));
  const float ang = (float)s * exp2f((float)j * NLOG2T_64);
  const float c = __cosf(ang), sn = __sinf(ang);
  const unsigned o = (unsigned)f2bf(x0*c - x1*sn) | ((unsigned)f2bf(x0*sn + x1*c) << 16);
  *(unsigned*)(ka + ((size_t)kv*S_ + s)*HD_ + 2*j) = o;
}

// ---------------- V transpose: qkv[s][5120+kv*128+d] -> vt[kv][d][s] -------------
__global__ __launch_bounds__(256) void vtrans_k(const unsigned short* __restrict__ qkv,
                                                unsigned short* __restrict__ vt){
  const int idx = blockIdx.x * 256 + threadIdx.x;
  const int s = idx & (S_-1), d = (idx >> 11) & (HD_-1), kv = idx >> 18;
  vt[idx] = qkv[(size_t)s*NQKV_ + (H_+KV_)*HD_ + kv*HD_ + d];
}

// ---------------- flash attention (causal, GQA), paired q-tiles ----------------
// grid (H, 16). Block p handles q-tiles (31-p) then (p), 64 rows each; wave w owns
// 16 rows. Every block does exactly 33 64-key units -> perfect balance. K/V LDS
// double-buffered (fragment-order granules, conflict-free ds_read_b128). Row-sum
// of P via MFMA against all-ones B-frag (no shuffle-sum tree). Q pre-scaled.
__device__ __forceinline__ void stage_kv(const unsigned short* __restrict__ ka,
                                         const unsigned short* __restrict__ vt,
                                         unsigned short* sKbuf, unsigned short* sVbuf,
                                         int hk, int t0, int wave, int lane){
  const int l15 = lane & 15, quad = lane >> 4;
  #pragma unroll
  for (int j = 0; j < 4; j++){
    const int c = wave*4 + j;                 // (kt,kk) = (c>>2, c&3)
    const int kt = c >> 2, kk = c & 3;
    gl_lds16(ka + (size_t)(hk*S_ + t0 + kt*16 + l15)*HD_ + kk*32 + quad*8,
             sKbuf + c*512);
  }
  #pragma unroll
  for (int j = 0; j < 4; j++){
    const int c = wave*4 + j;                 // (nt,kk2) = (c>>1, c&1)
    const int nt = c >> 1, kk2 = c & 1;
    gl_lds16(vt + (size_t)(hk*HD_ + nt*16 + l15)*S_ + t0 + kk2*32 + quad*8,
             sVbuf + c*512);
  }
}

__global__ __launch_bounds__(256, 2) void attn_k(const unsigned short* __restrict__ qa,
                                                 const unsigned short* __restrict__ ka,
                                                 const unsigned short* __restrict__ vt,
                                                 unsigned short* __restrict__ out){
  const int h = blockIdx.x, p = blockIdx.y;
  const int tid = threadIdx.x, wave = tid >> 6, lane = tid & 63;
  const int l15 = lane & 15, quad = lane >> 4;
  const int hk = h >> 2;                      // N_REP = 4
  const int nbB = 32 - p;                     // units for heavy tile (31-p)
  const int total = nbB + p + 1;              // 33 always

  __shared__ __align__(16) unsigned short sK[2][8192];   // 16KB x2
  __shared__ __align__(16) unsigned short sV[2][8192];   // 16KB x2
  __shared__ __align__(16) unsigned short sP[4][1024];   // 2KB per wave
  unsigned short* pl = &sP[wave][0];

  short8 ones;
  #pragma unroll
  for (int i = 0; i < 8; i++) ones[i] = (short)0x3F80;   // bf16 1.0

  int tile = 31 - p;
  short8 qf[4];
  {
    const unsigned short* qb = qa + (size_t)(h*S_ + tile*64 + wave*16 + l15)*HD_ + quad*8;
    #pragma unroll
    for (int kk = 0; kk < 4; kk++) qf[kk] = *(const short8*)(qb + kk*32);
  }

  v4f O[8];
  #pragma unroll
  for (int nt = 0; nt < 8; nt++) O[nt] = (v4f){0.f,0.f,0.f,0.f};
  float mrow[4], lrow[4];
  #pragma unroll
  for (int r = 0; r < 4; r++){ mrow[r] = -1e30f; lrow[r] = 0.f; }

  stage_kv(ka, vt, sK[0], sV[0], hk, 0, wave, lane);
  __syncthreads();

  for (int u = 0; u < total; ++u){
    const int cur = u & 1;
    if (u + 1 < total){
      const int b2 = (u + 1 < nbB) ? u + 1 : u + 1 - nbB;
      stage_kv(ka, vt, sK[cur^1], sV[cur^1], hk, b2*64, wave, lane);
    }

    // ---- QK^T: S[16 q-rows x 64 keys] ----
    const unsigned short* Kb = &sK[cur][0];
    v4f sc[4];
    #pragma unroll
    for (int kt = 0; kt < 4; kt++) sc[kt] = (v4f){0.f,0.f,0.f,0.f};
    #pragma unroll
    for (int kt = 0; kt < 4; kt++)
      #pragma unroll
      for (int kk = 0; kk < 4; kk++){
        const short8 kf = *(const short8*)(Kb + (kt*4 + kk)*512 + lane*8);
        sc[kt] = __builtin_amdgcn_mfma_f32_16x16x32_bf16(qf[kk], kf, sc[kt], 0, 0, 0);
      }

    // ---- online softmax (exp2 domain; Q pre-scaled) ----
    const bool diag = (u == nbB - 1) || (u == total - 1);   // wave-uniform
    float alpha[4];
    #pragma unroll
    for (int r = 0; r < 4; r++){
      float a0 = sc[0][r], a1 = sc[1][r], a2 = sc[2][r], a3 = sc[3][r];
      if (diag){
        const int rloc = wave*16 + quad*4 + r;
        if (     l15 > rloc) a0 = -1e30f;
        if (16 + l15 > rloc) a1 = -1e30f;
        if (32 + l15 > rloc) a2 = -1e30f;
        if (48 + l15 > rloc) a3 = -1e30f;
      }
      float mx = fmaxf(fmaxf(a0, a1), fmaxf(a2, a3));
      #pragma unroll
      for (int off = 1; off < 16; off <<= 1) mx = fmaxf(mx, __shfl_xor(mx, off, 16));
      const float mnew = fmaxf(mrow[r], mx);
      alpha[r] = exp2f(mrow[r] - mnew);
      mrow[r] = mnew;
      const float e0 = exp2f(a0 - mnew);
      const float e1 = exp2f(a1 - mnew);
      const float e2 = exp2f(a2 - mnew);
      const float e3 = exp2f(a3 - mnew);
      const int mr = (quad*4 + r)*8 + (l15 & 7);
      const int hi = (l15 >> 3) * 128;
      pl[      hi       + mr] = f2bf(e0);     // kt=0: kk2=0, q'=0..1
      pl[      hi + 256 + mr] = f2bf(e1);     // kt=1: kk2=0, q'=2..3
      pl[512 + hi       + mr] = f2bf(e2);     // kt=2: kk2=1, q'=0..1
      pl[512 + hi + 256 + mr] = f2bf(e3);     // kt=3: kk2=1, q'=2..3
    }
    #pragma unroll
    for (int nt = 0; nt < 8; nt++)
      #pragma unroll
      for (int r = 0; r < 4; r++) O[nt][r] *= alpha[r];

    __builtin_amdgcn_s_waitcnt(0xC07F);       // lgkmcnt(0): per-wave P region ready
    const short8 pf0 = *(const short8*)(pl + lane*8);
    const short8 pf1 = *(const short8*)(pl + 512 + lane*8);

    // ---- row-sum of P via ones-MFMA (every lane gets its row's sum) ----
    v4f rs = (v4f){0.f,0.f,0.f,0.f};
    rs = __builtin_amdgcn_mfma_f32_16x16x32_bf16(pf0, ones, rs, 0, 0, 0);
    rs = __builtin_amdgcn_mfma_f32_16x16x32_bf16(pf1, ones, rs, 0, 0, 0);

    // ---- PV: O[16 q-rows x 128 dims] ----
    const unsigned short* Vb = &sV[cur][0];
    #pragma unroll
    for (int nt = 0; nt < 8; nt++){
      const short8 vf0 = *(const short8*)(Vb + (nt*2    )*512 + lane*8);
      const short8 vf1 = *(const short8*)(Vb + (nt*2 + 1)*512 + lane*8);
      O[nt] = __builtin_amdgcn_mfma_f32_16x16x32_bf16(pf0, vf0, O[nt], 0, 0, 0);
      O[nt] = __builtin_amdgcn_mfma_f32_16x16x32_bf16(pf1, vf1, O[nt], 0, 0, 0);
    }
    #pragma unroll
    for (int r = 0; r < 4; r++) lrow[r] = lrow[r]*alpha[r] + rs[r];

    __syncthreads();   // all waves done with cur before it is overwritten

    if (u == nbB - 1){                        // finalize heavy tile, switch to light
      #pragma unroll
      for (int r = 0; r < 4; r++){
        const float inv = 1.0f / lrow[r];
        const size_t row = (size_t)(tile*64 + wave*16 + quad*4 + r);
        #pragma unroll
        for (int nt = 0; nt < 8; nt++)
          out[row*D_ + h*HD_ + nt*16 + l15] = f2bf(O[nt][r] * inv);
      }
      tile = p;
      const unsigned short* qb = qa + (size_t)(h*S_ + tile*64 + wave*16 + l15)*HD_ + quad*8;
      #pragma unroll
      for (int kk = 0; kk < 4; kk++) qf[kk] = *(const short8*)(qb + kk*32);
      #pragma unroll
      for (int nt = 0; nt < 8; nt++) O[nt] = (v4f){0.f,0.f,0.f,0.f};
      #pragma unroll
      for (int r = 0; r < 4; r++){ mrow[r] = -1e30f; lrow[r] = 0.f; }
    }
  }

  #pragma unroll
  for (int r = 0; r < 4; r++){
    const float inv = 1.0f / lrow[r];
    const size_t row = (size_t)(tile*64 + wave*16 + quad*4 + r);
    #pragma unroll
    for (int nt = 0; nt < 8; nt++)
      out[row*D_ + h*HD_ + nt*16 + l15] = f2bf(O[nt][r] * inv);
  }
}

// ---------------- launch ----------------
// Workspace map (MiB): [0,16) h_bf16 | [16,64) wqkv_bf16 (later: [16,48) wo_bf16,
// [48,64) attn_bf16) | [64,88) qkv_bf16 | [88,104) qa | [104,108) ka | [108,112) vt.
extern "C" void kernel_launch(void* const* d_in, const int* in_sizes, int n_in,
                              void* d_out, int out_size, void* d_ws, size_t ws_size,
                              hipStream_t stream){
  (void)in_sizes; (void)n_in; (void)out_size; (void)ws_size;
  const float* hidden = (const float*)d_in[0];
  const float* norm_w = (const float*)d_in[1];
  const float* wq = (const float*)d_in[2];
  const float* wk = (const float*)d_in[3];
  const float* wv = (const float*)d_in[4];
  const float* wo = (const float*)d_in[5];

  char* ws = (char*)d_ws;
  unsigned short* h_bf  = (unsigned short*)(ws);
  unsigned short* wqkv  = (unsigned short*)(ws + (size_t)(16u) * 1048576u);
  unsigned short* qkv   = (unsigned short*)(ws + (size_t)(64u) * 1048576u);
  unsigned short* qa    = (unsigned short*)(ws + (size_t)(88u) * 1048576u);
  unsigned short* ka    = (unsigned short*)(ws + (size_t)(104u) * 1048576u);
  unsigned short* vt    = (unsigned short*)(ws + (size_t)(108u) * 1048576u);
  unsigned short* wo_bf = (unsigned short*)(ws + (size_t)(16u) * 1048576u);  // reuse
  unsigned short* attnb = (unsigned short*)(ws + (size_t)(48u) * 1048576u);  // reuse

  rmsnorm_k<<<S_, 256, 0, stream>>>(hidden, norm_w, h_bf);

  cast_k<<<(D_*D_/4)/256, 256, 0, stream>>>(wq, wqkv, D_*D_/4);
  cast_k<<<(KV_*HD_*D_/4)/256, 256, 0, stream>>>(wk, wqkv + (size_t)H_*HD_*D_, KV_*HD_*D_/4);
  cast_k<<<(KV_*HD_*D_/4)/256, 256, 0, stream>>>(wv, wqkv + (size_t)(H_+KV_)*HD_*D_, KV_*HD_*D_/4);

  gemm_bt<<<dim3(NQKV_/128, S_/128), 256, 0, stream>>>(h_bf, wqkv, qkv, D_, NQKV_, 0);

  rope_q_k<<<(S_*H_*64)/256, 256, 0, stream>>>(qkv, qa);
  rope_kk <<<(S_*KV_*64)/256, 256, 0, stream>>>(qkv, ka);
  vtrans_k<<<(KV_*HD_*S_)/256, 256, 0, stream>>>(qkv, vt);

  cast_k<<<(D_*D_/4)/256, 256, 0, stream>>>(wo, wo_bf, D_*D_/4);

  attn_k<<<dim3(H_, 16), 256, 0, stream>>>(qa, ka, vt, attnb);

  gemm_bt<<<dim3(D_/128, S_/128), 256, 0, stream>>>(attnb, wo_bf, d_out, D_, D_, 1);
}